// Round 4
// baseline (228.597 us; speedup 1.0000x reference)
//
#include <hip/hip_runtime.h>

#define NSEQ 2048
#define KDIM 1024
#define DH   64
#define NS   8
#define NR   2

typedef short bf16x8 __attribute__((ext_vector_type(8)));
typedef float f32x4  __attribute__((ext_vector_type(4)));

typedef unsigned short ushort_ma __attribute__((may_alias));
typedef bf16x8         bf16x8_ma __attribute__((may_alias));
typedef uint4          uint4_ma  __attribute__((may_alias));
typedef uint2          uint2_ma  __attribute__((may_alias));
typedef float4         float4_ma __attribute__((may_alias));

__device__ __forceinline__ unsigned short f2bf(float f) {
    unsigned int u = __builtin_bit_cast(unsigned int, f);
    u = (u + 0x7FFFu + ((u >> 16) & 1u)) >> 16;   // RTN-even
    return (unsigned short)u;
}
__device__ __forceinline__ float bf2f(unsigned short h) {
    unsigned int u = ((unsigned int)h) << 16;
    return __builtin_bit_cast(float, u);
}
__device__ __forceinline__ unsigned int cvt_pk_bf16(float lo, float hi) {
    unsigned int r;
    asm("v_cvt_pk_bf16_f32 %0, %1, %2" : "=v"(r) : "v"(lo), "v"(hi));
    return r;
}

// ============ prep 1: weight transpose + f32->bf16 ============
// Wt[1664][1024] = [(0.125*log2e)*Wsq | Wsk | Wrq | Wrv]^T  (bf16, B-operand [n][k])
// Wot[1024][512] = Wout^T
__global__ __launch_bounds__(256) void prep_w_k(
    const float* __restrict__ Wsq, const float* __restrict__ Wsk,
    const float* __restrict__ Wrq, const float* __restrict__ Wrv,
    const float* __restrict__ Wout,
    unsigned short* __restrict__ Wt, unsigned short* __restrict__ Wot)
{
    __shared__ float sT[64][65];
    const int tid = threadIdx.x;
    const int bid = blockIdx.x;

    const float* src; int ldw, k0, n0, scol, ldo;
    unsigned short* dst;
    float sc = 1.0f;
    if (bid < 416) {
        int kt = bid / 26, nt = bid % 26;
        k0 = kt * 64; n0 = nt * 64;
        if (n0 < 512)       { src = Wsq; ldw = 512; scol = n0;        sc = 0.125f * 1.44269504089f; }
        else if (n0 < 1024) { src = Wsk; ldw = 512; scol = n0 - 512;  }
        else if (n0 < 1536) { src = Wrq; ldw = 512; scol = n0 - 1024; }
        else                { src = Wrv; ldw = 128; scol = n0 - 1536; }
        dst = Wt; ldo = KDIM;
    } else {
        int r = bid - 416;
        int kt = r >> 4, nt = r & 15;
        k0 = kt * 64; n0 = nt * 64; scol = n0;
        src = Wout; ldw = KDIM;
        dst = Wot; ldo = 512;
    }

#pragma unroll
    for (int p = 0; p < 4; ++p) {
        int row = (tid >> 4) + p * 16;
        int col = (tid & 15) * 4;
        float4 v = *(const float4*)&src[(size_t)(k0 + row) * ldw + scol + col];
        sT[row][col + 0] = v.x; sT[row][col + 1] = v.y;
        sT[row][col + 2] = v.z; sT[row][col + 3] = v.w;
    }
    __syncthreads();

    {
        int n_l = tid >> 2, kg = (tid & 3) * 16;
        unsigned int w[8];
#pragma unroll
        for (int j = 0; j < 8; ++j) {
            unsigned short a = f2bf(sT[kg + 2 * j][n_l] * sc);
            unsigned short b = f2bf(sT[kg + 2 * j + 1][n_l] * sc);
            w[j] = (unsigned)a | ((unsigned)b << 16);
        }
        unsigned short* o = dst + (size_t)(n0 + n_l) * ldo + k0 + kg;
        *(uint4_ma*)o       = make_uint4(w[0], w[1], w[2], w[3]);
        *(uint4_ma*)(o + 8) = make_uint4(w[4], w[5], w[6], w[7]);
    }
}

// ============ prep 2: x -> bf16 hi/lo planes ============
__global__ __launch_bounds__(256) void prep_x_k(
    const float* __restrict__ x,
    unsigned short* __restrict__ xh, unsigned short* __restrict__ xl)
{
    const int total = 4096 * KDIM / 4;
    int idx = blockIdx.x * 256 + threadIdx.x;
    for (int i = idx; i < total; i += gridDim.x * 256) {
        float4 v = ((const float4_ma*)x)[i];
        ushort4 h, l;
        h.x = f2bf(v.x); l.x = f2bf(v.x - bf2f(h.x));
        h.y = f2bf(v.y); l.y = f2bf(v.y - bf2f(h.y));
        h.z = f2bf(v.z); l.z = f2bf(v.z - bf2f(h.z));
        h.w = f2bf(v.w); l.w = f2bf(v.w - bf2f(h.w));
        ((ushort4*)xh)[i] = h;
        ((ushort4*)xl)[i] = l;
    }
}

// ============ Kernel 1: projection GEMM (bf16 MFMA, split-x) ============
__global__ __launch_bounds__(256) void proj_mfma_k(
    const unsigned short* __restrict__ xh, const unsigned short* __restrict__ xl,
    const unsigned short* __restrict__ Wt,
    unsigned short* __restrict__ Qb, unsigned short* __restrict__ Kb,
    float* __restrict__ RQ, unsigned short* __restrict__ Vt)
{
    __shared__ __align__(16) char smem[40960];
    const int tid = threadIdx.x;
    const int bn = blockIdx.x, bm = blockIdx.y;
    const int wid = tid >> 6, lane = tid & 63;
    const int wm = wid >> 1, wn = wid & 1;
    const int lrow = lane & 15, lgrp = lane >> 4;

    f32x4 acc[4][2];
#pragma unroll
    for (int i = 0; i < 4; ++i)
#pragma unroll
        for (int j = 0; j < 2; ++j) acc[i][j] = (f32x4){0.f, 0.f, 0.f, 0.f};

    for (int kt = 0; kt < KDIM / 64; ++kt) {
        __syncthreads();
#pragma unroll
        for (int p = 0; p < 4; ++p) {
            int c = tid + p * 256;
            int r = c >> 3, cc = c & 7;
            int off = (r * 128 + cc * 16) ^ ((r & 7) << 4);
            size_t g = (size_t)(bm * 128 + r) * KDIM + kt * 64 + cc * 8;
            *(uint4_ma*)(smem + off)         = *(const uint4_ma*)(xh + g);
            *(uint4_ma*)(smem + 16384 + off) = *(const uint4_ma*)(xl + g);
        }
#pragma unroll
        for (int p = 0; p < 2; ++p) {
            int c = tid + p * 256;
            int r = c >> 3, cc = c & 7;
            *(uint4_ma*)(smem + 32768 + ((r * 128 + cc * 16) ^ ((r & 7) << 4))) =
                *(const uint4_ma*)(Wt + (size_t)(bn * 64 + r) * KDIM + kt * 64 + cc * 8);
        }
        __syncthreads();
#pragma unroll
        for (int ks = 0; ks < 2; ++ks) {
            bf16x8 bfr[2];
#pragma unroll
            for (int nf = 0; nf < 2; ++nf) {
                int rb = wn * 32 + nf * 16 + lrow;
                bfr[nf] = *(bf16x8_ma*)(smem + 32768 + ((rb * 128 + ks * 64 + lgrp * 16) ^ ((rb & 7) << 4)));
            }
#pragma unroll
            for (int mf = 0; mf < 4; ++mf) {
                int ra = wm * 64 + mf * 16 + lrow;
                int offa = (ra * 128 + ks * 64 + lgrp * 16) ^ ((ra & 7) << 4);
                bf16x8 ah = *(bf16x8_ma*)(smem + offa);
                bf16x8 al = *(bf16x8_ma*)(smem + 16384 + offa);
#pragma unroll
                for (int nf = 0; nf < 2; ++nf) {
                    acc[mf][nf] = __builtin_amdgcn_mfma_f32_16x16x32_bf16(ah, bfr[nf], acc[mf][nf], 0, 0, 0);
                    acc[mf][nf] = __builtin_amdgcn_mfma_f32_16x16x32_bf16(al, bfr[nf], acc[mf][nf], 0, 0, 0);
                }
            }
        }
    }

    const int g = bn >> 3;   // 0:Q 1:K 2:RQ 3:V
#pragma unroll
    for (int mf = 0; mf < 4; ++mf) {
#pragma unroll
        for (int nf = 0; nf < 2; ++nf) {
            int j0 = bn * 64 + wn * 32 + nf * 16 + lrow;
            int m0 = bm * 128 + wm * 64 + mf * 16 + lgrp * 4;
            if (g == 3) {
                int dv = j0 - 1536;
                int bb = m0 >> 11, seq = m0 & (NSEQ - 1);
                ushort4 h;
                h.x = f2bf(acc[mf][nf][0]); h.y = f2bf(acc[mf][nf][1]);
                h.z = f2bf(acc[mf][nf][2]); h.w = f2bf(acc[mf][nf][3]);
                *(ushort4*)&Vt[((size_t)bb * 128 + dv) * NSEQ + seq] = h;
            } else {
                int s = (j0 >> 6) & 7, d = j0 & 63;
#pragma unroll
                for (int r = 0; r < 4; ++r) {
                    int m = m0 + r;
                    int bb = m >> 11, seq = m & (NSEQ - 1);
                    size_t idx = (((size_t)(bb * NS + s)) * NSEQ + seq) * DH + d;
                    if (g == 2)      RQ[idx] = acc[mf][nf][r];
                    else if (g == 0) Qb[idx] = f2bf(acc[mf][nf][r]);
                    else             Kb[idx] = f2bf(acc[mf][nf][r]);
                }
            }
        }
    }
}

// ============ Kernel 2: MFMA flash attention (swapped operands) + retrieval ============
// 4 waves, QBLK=64 (wave owns q = wid*16 + lrow). S^T = mfma(K,Q): lane holds 16 kv
// values for ONE q row -> in-lane softmax + 2 shfls. O^T = mfma(V^T, P): stats scalar.
// LDS 32KB: sK[64][64] @0 | sV[128][64] @8192 | sP[16][64]/wave @24576+wid*2048.
// Epilogue: Ol @wid*4096, Wrk f32 @16384. Rows swizzled ^((row&7)<<4).
__global__ __launch_bounds__(256) void attn_mfma_k(
    const unsigned short* __restrict__ Qb, const unsigned short* __restrict__ Kb,
    const unsigned short* __restrict__ Vt, const float* __restrict__ RQ,
    const float* __restrict__ Wrk, unsigned short* __restrict__ O1b)
{
    __shared__ __align__(16) char smem[32768];
    const int tid = threadIdx.x;
    const int qt = blockIdx.x, s = blockIdx.y, b = blockIdx.z;
    const int wid = tid >> 6, lane = tid & 63;
    const int lrow = lane & 15, lgrp = lane >> 4;

    const unsigned short* Qg = Qb + (((size_t)(b * NS + s)) * NSEQ + qt * 64) * DH;
    const unsigned short* Kg = Kb + (((size_t)(b * NS + s)) * NSEQ) * DH;
    const unsigned short* Vg = Vt + (size_t)b * 128 * NSEQ;

    // Q fragments in registers (B-operand): q = wid*16 + lrow, k = kk*32 + lgrp*8
    bf16x8 qf[2];
    {
        const unsigned short* qrow = Qg + (wid * 16 + lrow) * DH + lgrp * 8;
        qf[0] = *(const bf16x8_ma*)(qrow);
        qf[1] = *(const bf16x8_ma*)(qrow + 32);
    }

    // staging pointers / LDS offsets (r0 = tid>>3 in 0..31, cc = tid&7)
    const int r0 = tid >> 3, cc = tid & 7;
    const unsigned short* kp = Kg + (size_t)r0 * DH + cc * 8;     // +kt*64*DH
    const unsigned short* vp = Vg + (size_t)r0 * NSEQ + cc * 8;   // +t*32*NSEQ +kt*64
    const int offk = (r0 * 128 + cc * 16) ^ ((r0 & 7) << 4);      // rows r0, r0+32 at +4096
    const int offv = 8192 + offk;                                  // d rows r0+32t at +4096*t
    char* sPw = smem + 24576 + wid * 2048;

    uint4 kreg[2], vreg[4];
    kreg[0] = *(const uint4_ma*)(kp);
    kreg[1] = *(const uint4_ma*)(kp + 32 * DH);
#pragma unroll
    for (int t = 0; t < 4; ++t)
        vreg[t] = *(const uint4_ma*)(vp + (size_t)(32 * t) * NSEQ);

    f32x4 oacc[8];
#pragma unroll
    for (int df = 0; df < 8; ++df) oacc[df] = (f32x4){0.f, 0.f, 0.f, 0.f};
    float m_ = -1e30f, l_ = 0.f;

    const int NT = NSEQ / 64;
    for (int kt = 0; kt < NT; ++kt) {
        __syncthreads();   // previous tile's LDS reads done
        *(uint4_ma*)(smem + offk)        = kreg[0];
        *(uint4_ma*)(smem + offk + 4096) = kreg[1];
#pragma unroll
        for (int t = 0; t < 4; ++t)
            *(uint4_ma*)(smem + offv + t * 4096) = vreg[t];
        if (kt + 1 < NT) {
            kreg[0] = *(const uint4_ma*)(kp + (size_t)(kt + 1) * 64 * DH);
            kreg[1] = *(const uint4_ma*)(kp + (size_t)(kt + 1) * 64 * DH + 32 * DH);
#pragma unroll
            for (int t = 0; t < 4; ++t)
                vreg[t] = *(const uint4_ma*)(vp + (size_t)(32 * t) * NSEQ + (kt + 1) * 64);
        }
        __syncthreads();   // tile ready

        // ---- S^T = K x Q^T : lane holds S[q=lrow][kv = nf*16 + lgrp*4 + r] ----
        f32x4 st[4];
#pragma unroll
        for (int nf = 0; nf < 4; ++nf) st[nf] = (f32x4){0.f, 0.f, 0.f, 0.f};
        __builtin_amdgcn_s_setprio(1);
#pragma unroll
        for (int kk = 0; kk < 2; ++kk) {
#pragma unroll
            for (int nf = 0; nf < 4; ++nf) {
                int row = nf * 16 + lrow;
                bf16x8 kf = *(bf16x8_ma*)(smem + ((row * 128 + kk * 64 + lgrp * 16) ^ ((row & 7) << 4)));
                st[nf] = __builtin_amdgcn_mfma_f32_16x16x32_bf16(kf, qf[kk], st[nf], 0, 0, 0);
            }
        }
        __builtin_amdgcn_s_setprio(0);

        // ---- online softmax, log2 domain (per-lane row; 2+2 shfls) ----
        float mx = st[0][0];
#pragma unroll
        for (int nf = 0; nf < 4; ++nf)
#pragma unroll
            for (int r = 0; r < 4; ++r) mx = fmaxf(mx, st[nf][r]);
        mx = fmaxf(mx, __shfl_xor(mx, 16));
        mx = fmaxf(mx, __shfl_xor(mx, 32));
        float mnew = fmaxf(m_, mx);
        float alpha = __builtin_exp2f(m_ - mnew);
        float rs = 0.f;
#pragma unroll
        for (int nf = 0; nf < 4; ++nf)
#pragma unroll
            for (int r = 0; r < 4; ++r) {
                float p = __builtin_exp2f(st[nf][r] - mnew);
                st[nf][r] = p;
                rs += p;
            }
        rs += __shfl_xor(rs, 16);
        rs += __shfl_xor(rs, 32);
        l_ = l_ * alpha + rs;
        m_ = mnew;
#pragma unroll
        for (int df = 0; df < 8; ++df) oacc[df] = oacc[df] * alpha;

        // ---- P -> LDS (packed b64, wave-local) ----
        const int pswz = (lrow & 7) << 4;
#pragma unroll
        for (int nf = 0; nf < 4; ++nf) {
            uint2 w;
            w.x = cvt_pk_bf16(st[nf][0], st[nf][1]);
            w.y = cvt_pk_bf16(st[nf][2], st[nf][3]);
            *(uint2_ma*)(sPw + ((lrow * 128 + nf * 32 + lgrp * 8) ^ pswz)) = w;
        }

        // ---- O^T += V^T x P^T : lane holds O[q=lrow][d = df*16 + lgrp*4 + r] ----
        __builtin_amdgcn_s_setprio(1);
#pragma unroll
        for (int kkv = 0; kkv < 2; ++kkv) {
            bf16x8 pf = *(bf16x8_ma*)(sPw + ((lrow * 128 + kkv * 64 + lgrp * 16) ^ pswz));
#pragma unroll
            for (int df = 0; df < 8; ++df) {
                int row = df * 16 + lrow;
                bf16x8 vf = *(bf16x8_ma*)(smem + 8192 + ((row * 128 + kkv * 64 + lgrp * 16) ^ ((row & 7) << 4)));
                oacc[df] = __builtin_amdgcn_mfma_f32_16x16x32_bf16(vf, pf, oacc[df], 0, 0, 0);
            }
        }
        __builtin_amdgcn_s_setprio(0);
    }

    // ================= fused retrieval epilogue =================
    __syncthreads();   // all sK/sV/sP reads done

    // normalized retrieved -> Ol bf16 [16 q][128 d] per wave
    float invl = 1.f / l_;
    char* OlW = smem + wid * 4096;
    const int oswz = (lrow & 7) << 4;
#pragma unroll
    for (int df = 0; df < 8; ++df) {
        uint2 w;
        w.x = cvt_pk_bf16(oacc[df][0] * invl, oacc[df][1] * invl);
        w.y = cvt_pk_bf16(oacc[df][2] * invl, oacc[df][3] * invl);
        *(uint2_ma*)(OlW + ((lrow * 256 + df * 32 + lgrp * 8) ^ oswz)) = w;
    }
    // stage Wrk f32 [64][64] at +16384
#pragma unroll
    for (int t = 0; t < 4; ++t) {
        int c = tid + t * 256;
        int e = c >> 4, dd = (c & 15) * 4;
        *(float4_ma*)(smem + 16384 + e * 256 + dd * 4) = *(const float4_ma*)(Wrk + e * 64 + dd);
    }
    __syncthreads();

    {
        int row = lrow;
        int part = lgrp;
        int n = qt * 64 + wid * 16 + row;
        const float* rqg = RQ + ((((size_t)(b * NS + s)) * NSEQ) + n) * DH + part * 16;
        float rq[16];
#pragma unroll
        for (int c4 = 0; c4 < 4; ++c4) {
            float4 t4 = *(const float4_ma*)(rqg + c4 * 4);
            rq[c4 * 4 + 0] = t4.x; rq[c4 * 4 + 1] = t4.y;
            rq[c4 * 4 + 2] = t4.z; rq[c4 * 4 + 3] = t4.w;
        }
        float rk0[16], rk1[16];
#pragma unroll
        for (int j = 0; j < 16; ++j) { rk0[j] = 0.f; rk1[j] = 0.f; }
        const int rswz = (row & 7) << 4;
        for (int e = 0; e < 64; ++e) {
            float v0 = bf2f(*(ushort_ma*)(OlW + ((row * 256 + e * 2) ^ rswz)));
            float v1 = bf2f(*(ushort_ma*)(OlW + ((row * 256 + 128 + e * 2) ^ rswz)));
            const char* wr = smem + 16384 + e * 256 + part * 64;
            float4 w0 = *(const float4_ma*)(wr);
            float4 w1 = *(const float4_ma*)(wr + 16);
            float4 w2 = *(const float4_ma*)(wr + 32);
            float4 w3 = *(const float4_ma*)(wr + 48);
            float wv[16] = {w0.x, w0.y, w0.z, w0.w, w1.x, w1.y, w1.z, w1.w,
                            w2.x, w2.y, w2.z, w2.w, w3.x, w3.y, w3.z, w3.w};
#pragma unroll
            for (int j = 0; j < 16; ++j) {
                rk0[j] += v0 * wv[j];
                rk1[j] += v1 * wv[j];
            }
        }
        float s0 = 0.f, s1 = 0.f;
#pragma unroll
        for (int j = 0; j < 16; ++j) { s0 += rq[j] * rk0[j]; s1 += rq[j] * rk1[j]; }
        s0 += __shfl_xor(s0, 16); s0 += __shfl_xor(s0, 32);
        s1 += __shfl_xor(s1, 16); s1 += __shfl_xor(s1, 32);
        float r0 = s0 * 0.125f, r1 = s1 * 0.125f;
        float mm = fmaxf(r0, r1);
        float e0 = __expf(r0 - mm), e1 = __expf(r1 - mm);
        float rinv = 1.f / (e0 + e1);
        float a0 = e0 * rinv, a1 = e1 * rinv;

        unsigned short* dst = O1b + ((size_t)(b * NSEQ + n)) * (NS * DH) + s * DH + part * 16;
#pragma unroll
        for (int c4 = 0; c4 < 4; ++c4) {
            ushort4 o4;
            float t[4];
#pragma unroll
            for (int k = 0; k < 4; ++k) {
                int d = part * 16 + c4 * 4 + k;
                float v0 = bf2f(*(ushort_ma*)(OlW + ((row * 256 + d * 2) ^ rswz)));
                float v1 = bf2f(*(ushort_ma*)(OlW + ((row * 256 + (64 + d) * 2) ^ rswz)));
                t[k] = a0 * v0 + a1 * v1;
            }
            o4.x = f2bf(t[0]); o4.y = f2bf(t[1]); o4.z = f2bf(t[2]); o4.w = f2bf(t[3]);
            *(ushort4*)(dst + c4 * 4) = o4;
        }
    }
}

// ============ Kernel 3: output GEMM (bf16 MFMA) ============
__global__ __launch_bounds__(256) void out_mfma_k(
    const unsigned short* __restrict__ A, const unsigned short* __restrict__ Bw,
    float* __restrict__ C)
{
    __shared__ __align__(16) char smem[24576];
    const int tid = threadIdx.x;
    const int bn = blockIdx.x, bm = blockIdx.y;
    const int wid = tid >> 6, lane = tid & 63;
    const int wm = wid >> 1, wn = wid & 1;
    const int lrow = lane & 15, lgrp = lane >> 4;
    const int KD = NS * DH;   // 512

    f32x4 acc[4][2];
#pragma unroll
    for (int i = 0; i < 4; ++i)
#pragma unroll
        for (int j = 0; j < 2; ++j) acc[i][j] = (f32x4){0.f, 0.f, 0.f, 0.f};

    for (int kt = 0; kt < KD / 64; ++kt) {
        __syncthreads();
#pragma unroll
        for (int p = 0; p < 4; ++p) {
            int c = tid + p * 256;
            int r = c >> 3, cc = c & 7;
            *(uint4_ma*)(smem + ((r * 128 + cc * 16) ^ ((r & 7) << 4))) =
                *(const uint4_ma*)(A + (size_t)(bm * 128 + r) * KD + kt * 64 + cc * 8);
        }
#pragma unroll
        for (int p = 0; p < 2; ++p) {
            int c = tid + p * 256;
            int r = c >> 3, cc = c & 7;
            *(uint4_ma*)(smem + 16384 + ((r * 128 + cc * 16) ^ ((r & 7) << 4))) =
                *(const uint4_ma*)(Bw + (size_t)(bn * 64 + r) * KD + kt * 64 + cc * 8);
        }
        __syncthreads();
#pragma unroll
        for (int ks = 0; ks < 2; ++ks) {
            bf16x8 bfr[2];
#pragma unroll
            for (int nf = 0; nf < 2; ++nf) {
                int rb = wn * 32 + nf * 16 + lrow;
                bfr[nf] = *(bf16x8_ma*)(smem + 16384 + ((rb * 128 + ks * 64 + lgrp * 16) ^ ((rb & 7) << 4)));
            }
#pragma unroll
            for (int mf = 0; mf < 4; ++mf) {
                int ra = wm * 64 + mf * 16 + lrow;
                bf16x8 af = *(bf16x8_ma*)(smem + ((ra * 128 + ks * 64 + lgrp * 16) ^ ((ra & 7) << 4)));
#pragma unroll
                for (int nf = 0; nf < 2; ++nf)
                    acc[mf][nf] = __builtin_amdgcn_mfma_f32_16x16x32_bf16(af, bfr[nf], acc[mf][nf], 0, 0, 0);
            }
        }
    }

#pragma unroll
    for (int mf = 0; mf < 4; ++mf) {
#pragma unroll
        for (int nf = 0; nf < 2; ++nf) {
            int j0 = bn * 64 + wn * 32 + nf * 16 + lrow;
            int m0 = bm * 128 + wm * 64 + mf * 16 + lgrp * 4;
#pragma unroll
            for (int r = 0; r < 4; ++r)
                C[(size_t)(m0 + r) * KDIM + j0] = acc[mf][nf][r];
        }
    }
}

extern "C" void kernel_launch(void* const* d_in, const int* in_sizes, int n_in,
                              void* d_out, int out_size, void* d_ws, size_t ws_size,
                              hipStream_t stream)
{
    const float* x    = (const float*)d_in[0];
    const float* Wsq  = (const float*)d_in[1];
    const float* Wsk  = (const float*)d_in[2];
    const float* Wrv  = (const float*)d_in[3];
    const float* Wrq  = (const float*)d_in[4];
    const float* Wrk  = (const float*)d_in[5];
    const float* Wout = (const float*)d_in[6];
    float* out = (float*)d_out;

    // workspace layout (37.3 MB)
    float* RQ            = (float*)d_ws;                        // [2][8][2048][64] f32, 8 MB
    unsigned short* Wt   = (unsigned short*)(RQ + (size_t)2 * NS * NSEQ * DH);  // [1664][1024], 3.25 MB
    unsigned short* Wot  = Wt + (size_t)1664 * KDIM;            // [1024][512], 1 MB
    unsigned short* Qb   = Wot + (size_t)KDIM * 512;            // [2][8][2048][64], 4 MB
    unsigned short* Kb   = Qb + (size_t)2 * NS * NSEQ * DH;     // 4 MB
    unsigned short* Vtb  = Kb + (size_t)2 * NS * NSEQ * DH;     // [2][128][2048], 1 MB
    unsigned short* xh   = Vtb + (size_t)2 * 128 * NSEQ;        // [4096][1024], 8 MB
    unsigned short* xl   = xh + (size_t)4096 * KDIM;            // 8 MB
    unsigned short* O1b  = xh;  // alias: xh dead after proj_mfma_k

    prep_w_k<<<544, 256, 0, stream>>>(Wsq, Wsk, Wrq, Wrv, Wout, Wt, Wot);
    prep_x_k<<<2048, 256, 0, stream>>>(x, xh, xl);
    proj_mfma_k<<<dim3(26, 32), 256, 0, stream>>>(xh, xl, Wt, Qb, Kb, RQ, Vtb);
    attn_mfma_k<<<dim3(NSEQ / 64, NS, 2), 256, 0, stream>>>(Qb, Kb, Vtb, RQ, Wrk, O1b);
    out_mfma_k<<<dim3(16, 32), 256, 0, stream>>>(O1b, Wot, out);
}

// Round 5
// 193.034 us; speedup vs baseline: 1.1842x; 1.1842x over previous
//
#include <hip/hip_runtime.h>

#define NSEQ 2048
#define KDIM 1024
#define DH   64
#define NS   8
#define NR   2

typedef short bf16x8 __attribute__((ext_vector_type(8)));
typedef float f32x4  __attribute__((ext_vector_type(4)));

typedef unsigned short ushort_ma __attribute__((may_alias));
typedef bf16x8         bf16x8_ma __attribute__((may_alias));
typedef uint4          uint4_ma  __attribute__((may_alias));
typedef uint2          uint2_ma  __attribute__((may_alias));
typedef float4         float4_ma __attribute__((may_alias));

__device__ __forceinline__ unsigned short f2bf(float f) {
    unsigned int u = __builtin_bit_cast(unsigned int, f);
    u = (u + 0x7FFFu + ((u >> 16) & 1u)) >> 16;   // RTN-even
    return (unsigned short)u;
}
__device__ __forceinline__ float bf2f(unsigned short h) {
    unsigned int u = ((unsigned int)h) << 16;
    return __builtin_bit_cast(float, u);
}
__device__ __forceinline__ unsigned int cvt_pk_bf16(float lo, float hi) {
    unsigned int r;
    asm("v_cvt_pk_bf16_f32 %0, %1, %2" : "=v"(r) : "v"(lo), "v"(hi));
    return r;
}

// ============ prep 1: weight transpose + f32->bf16 ============
// Wt[1664][1024] = [(0.125*log2e)*Wsq | Wsk | (skip Wrq sect) | Wrv]^T
// Wot[1024][512] = Wout^T
__global__ __launch_bounds__(256) void prep_w_k(
    const float* __restrict__ Wsq, const float* __restrict__ Wsk,
    const float* __restrict__ Wrq, const float* __restrict__ Wrv,
    const float* __restrict__ Wout,
    unsigned short* __restrict__ Wt, unsigned short* __restrict__ Wot)
{
    __shared__ float sT[64][65];
    const int tid = threadIdx.x;
    const int bid = blockIdx.x;

    const float* src; int ldw, k0, n0, scol, ldo;
    unsigned short* dst;
    float sc = 1.0f;
    if (bid < 416) {
        int kt = bid / 26, nt = bid % 26;
        k0 = kt * 64; n0 = nt * 64;
        if (n0 >= 1024 && n0 < 1536) return;   // Wrq section written by prep_wc_k
        if (n0 < 512)       { src = Wsq; ldw = 512; scol = n0;        sc = 0.125f * 1.44269504089f; }
        else if (n0 < 1024) { src = Wsk; ldw = 512; scol = n0 - 512;  }
        else                { src = Wrv; ldw = 128; scol = n0 - 1536; }
        dst = Wt; ldo = KDIM;
    } else {
        int r = bid - 416;
        int kt = r >> 4, nt = r & 15;
        k0 = kt * 64; n0 = nt * 64; scol = n0;
        src = Wout; ldw = KDIM;
        dst = Wot; ldo = 512;
    }

#pragma unroll
    for (int p = 0; p < 4; ++p) {
        int row = (tid >> 4) + p * 16;
        int col = (tid & 15) * 4;
        float4 v = *(const float4*)&src[(size_t)(k0 + row) * ldw + scol + col];
        sT[row][col + 0] = v.x; sT[row][col + 1] = v.y;
        sT[row][col + 2] = v.z; sT[row][col + 3] = v.w;
    }
    __syncthreads();

    {
        int n_l = tid >> 2, kg = (tid & 3) * 16;
        unsigned int w[8];
#pragma unroll
        for (int j = 0; j < 8; ++j) {
            unsigned short a = f2bf(sT[kg + 2 * j][n_l] * sc);
            unsigned short b = f2bf(sT[kg + 2 * j + 1][n_l] * sc);
            w[j] = (unsigned)a | ((unsigned)b << 16);
        }
        unsigned short* o = dst + (size_t)(n0 + n_l) * ldo + k0 + kg;
        *(uint4_ma*)o       = make_uint4(w[0], w[1], w[2], w[3]);
        *(uint4_ma*)(o + 8) = make_uint4(w[4], w[5], w[6], w[7]);
    }
}

// ============ prep 1b: Wc_s = Wrq[:, s*64:+64] @ Wrk^T, into Wt rows [1024+s*64, +64) ============
// Wt[1024 + s*64 + dd][k] = (0.125*log2e) * sum_e Wrq[k][s*64+e] * Wrk[dd][e]
__global__ __launch_bounds__(256) void prep_wc_k(
    const float* __restrict__ Wrq, const float* __restrict__ Wrk,
    unsigned short* __restrict__ Wt)
{
    __shared__ float sQ[64][65];   // Wrq tile [k][e]
    __shared__ float sK[64][65];   // Wrk [dd][e]
    const int tid = threadIdx.x;
    const int s = blockIdx.x;          // 0..7
    const int k0 = blockIdx.y * 64;    // 0..960

#pragma unroll
    for (int p = 0; p < 4; ++p) {
        int row = (tid >> 4) + p * 16;
        int col = (tid & 15) * 4;
        float4 w = *(const float4*)&Wrk[(size_t)row * 64 + col];
        sK[row][col + 0] = w.x; sK[row][col + 1] = w.y;
        sK[row][col + 2] = w.z; sK[row][col + 3] = w.w;
        float4 q = *(const float4*)&Wrq[(size_t)(k0 + row) * 512 + s * 64 + col];
        sQ[row][col + 0] = q.x; sQ[row][col + 1] = q.y;
        sQ[row][col + 2] = q.z; sQ[row][col + 3] = q.w;
    }
    __syncthreads();

    const int dd = tid >> 2;           // output u-dim (row of Wt section)
    const int kq = (tid & 3) * 16;     // 16 k columns
    float acc[16];
#pragma unroll
    for (int j = 0; j < 16; ++j) acc[j] = 0.f;
    for (int e = 0; e < 64; ++e) {
        float w = sK[dd][e];
#pragma unroll
        for (int j = 0; j < 16; ++j) acc[j] += w * sQ[kq + j][e];
    }
    const float SC = 0.125f * 1.44269504089f;
    unsigned int w8[8];
#pragma unroll
    for (int j = 0; j < 8; ++j)
        w8[j] = (unsigned)f2bf(acc[2 * j] * SC) | ((unsigned)f2bf(acc[2 * j + 1] * SC) << 16);
    unsigned short* o = Wt + (size_t)(1024 + s * 64 + dd) * KDIM + k0 + kq;
    *(uint4_ma*)o       = make_uint4(w8[0], w8[1], w8[2], w8[3]);
    *(uint4_ma*)(o + 8) = make_uint4(w8[4], w8[5], w8[6], w8[7]);
}

// ============ prep 2: x -> bf16 hi/lo planes ============
__global__ __launch_bounds__(256) void prep_x_k(
    const float* __restrict__ x,
    unsigned short* __restrict__ xh, unsigned short* __restrict__ xl)
{
    const int total = 4096 * KDIM / 4;
    int idx = blockIdx.x * 256 + threadIdx.x;
    for (int i = idx; i < total; i += gridDim.x * 256) {
        float4 v = ((const float4_ma*)x)[i];
        ushort4 h, l;
        h.x = f2bf(v.x); l.x = f2bf(v.x - bf2f(h.x));
        h.y = f2bf(v.y); l.y = f2bf(v.y - bf2f(h.y));
        h.z = f2bf(v.z); l.z = f2bf(v.z - bf2f(h.z));
        h.w = f2bf(v.w); l.w = f2bf(v.w - bf2f(h.w));
        ((ushort4*)xh)[i] = h;
        ((ushort4*)xl)[i] = l;
    }
}

// ============ Kernel 1: projection GEMM (bf16 MFMA, split-x) ============
// outputs: Qb/Kb bf16 [b][s][n][64], RU f32 [b][s][n][64] (= x @ Wc, scaled), Vt bf16 [b][128][n]
__global__ __launch_bounds__(256) void proj_mfma_k(
    const unsigned short* __restrict__ xh, const unsigned short* __restrict__ xl,
    const unsigned short* __restrict__ Wt,
    unsigned short* __restrict__ Qb, unsigned short* __restrict__ Kb,
    float* __restrict__ RU, unsigned short* __restrict__ Vt)
{
    __shared__ __align__(16) char smem[40960];
    const int tid = threadIdx.x;
    const int bn = blockIdx.x, bm = blockIdx.y;
    const int wid = tid >> 6, lane = tid & 63;
    const int wm = wid >> 1, wn = wid & 1;
    const int lrow = lane & 15, lgrp = lane >> 4;

    f32x4 acc[4][2];
#pragma unroll
    for (int i = 0; i < 4; ++i)
#pragma unroll
        for (int j = 0; j < 2; ++j) acc[i][j] = (f32x4){0.f, 0.f, 0.f, 0.f};

    for (int kt = 0; kt < KDIM / 64; ++kt) {
        __syncthreads();
#pragma unroll
        for (int p = 0; p < 4; ++p) {
            int c = tid + p * 256;
            int r = c >> 3, cc = c & 7;
            int off = (r * 128 + cc * 16) ^ ((r & 7) << 4);
            size_t g = (size_t)(bm * 128 + r) * KDIM + kt * 64 + cc * 8;
            *(uint4_ma*)(smem + off)         = *(const uint4_ma*)(xh + g);
            *(uint4_ma*)(smem + 16384 + off) = *(const uint4_ma*)(xl + g);
        }
#pragma unroll
        for (int p = 0; p < 2; ++p) {
            int c = tid + p * 256;
            int r = c >> 3, cc = c & 7;
            *(uint4_ma*)(smem + 32768 + ((r * 128 + cc * 16) ^ ((r & 7) << 4))) =
                *(const uint4_ma*)(Wt + (size_t)(bn * 64 + r) * KDIM + kt * 64 + cc * 8);
        }
        __syncthreads();
#pragma unroll
        for (int ks = 0; ks < 2; ++ks) {
            bf16x8 bfr[2];
#pragma unroll
            for (int nf = 0; nf < 2; ++nf) {
                int rb = wn * 32 + nf * 16 + lrow;
                bfr[nf] = *(bf16x8_ma*)(smem + 32768 + ((rb * 128 + ks * 64 + lgrp * 16) ^ ((rb & 7) << 4)));
            }
#pragma unroll
            for (int mf = 0; mf < 4; ++mf) {
                int ra = wm * 64 + mf * 16 + lrow;
                int offa = (ra * 128 + ks * 64 + lgrp * 16) ^ ((ra & 7) << 4);
                bf16x8 ah = *(bf16x8_ma*)(smem + offa);
                bf16x8 al = *(bf16x8_ma*)(smem + 16384 + offa);
#pragma unroll
                for (int nf = 0; nf < 2; ++nf) {
                    acc[mf][nf] = __builtin_amdgcn_mfma_f32_16x16x32_bf16(ah, bfr[nf], acc[mf][nf], 0, 0, 0);
                    acc[mf][nf] = __builtin_amdgcn_mfma_f32_16x16x32_bf16(al, bfr[nf], acc[mf][nf], 0, 0, 0);
                }
            }
        }
    }

    const int g = bn >> 3;   // 0:Q 1:K 2:U 3:V
#pragma unroll
    for (int mf = 0; mf < 4; ++mf) {
#pragma unroll
        for (int nf = 0; nf < 2; ++nf) {
            int j0 = bn * 64 + wn * 32 + nf * 16 + lrow;
            int m0 = bm * 128 + wm * 64 + mf * 16 + lgrp * 4;
            if (g == 3) {
                int dv = j0 - 1536;
                int bb = m0 >> 11, seq = m0 & (NSEQ - 1);
                ushort4 h;
                h.x = f2bf(acc[mf][nf][0]); h.y = f2bf(acc[mf][nf][1]);
                h.z = f2bf(acc[mf][nf][2]); h.w = f2bf(acc[mf][nf][3]);
                *(ushort4*)&Vt[((size_t)bb * 128 + dv) * NSEQ + seq] = h;
            } else {
                int s = (j0 >> 6) & 7, d = j0 & 63;
#pragma unroll
                for (int r = 0; r < 4; ++r) {
                    int m = m0 + r;
                    int bb = m >> 11, seq = m & (NSEQ - 1);
                    size_t idx = (((size_t)(bb * NS + s)) * NSEQ + seq) * DH + d;
                    if (g == 2)      RU[idx] = acc[mf][nf][r];
                    else if (g == 0) Qb[idx] = f2bf(acc[mf][nf][r]);
                    else             Kb[idx] = f2bf(acc[mf][nf][r]);
                }
            }
        }
    }
}

// ============ Kernel 2: MFMA flash attention, dbuf K/V, fused retrieval via U ============
// 4 waves, QBLK=64 (wave owns q = wid*16 + lrow). S^T = mfma(K,Q), O^T = mfma(V^T,P):
// per-lane scalar softmax stats. LDS 57344 B:
//   K dbuf 2x[64][64]bf16 @0/@8192 | V dbuf 2x[128][64]bf16 @16384/@32768
//   sP [16][64]bf16 per wave @49152 + wid*2048.  Rows swizzled ^((row&7)<<4).
__global__ __launch_bounds__(256) void attn_mfma_k(
    const unsigned short* __restrict__ Qb, const unsigned short* __restrict__ Kb,
    const unsigned short* __restrict__ Vt, const float* __restrict__ RU,
    unsigned short* __restrict__ O1b)
{
    __shared__ __align__(16) char smem[57344];
    const int tid = threadIdx.x;
    const int qt = blockIdx.x, s = blockIdx.y, b = blockIdx.z;
    const int wid = tid >> 6, lane = tid & 63;
    const int lrow = lane & 15, lgrp = lane >> 4;

    const unsigned short* Qg = Qb + (((size_t)(b * NS + s)) * NSEQ + qt * 64) * DH;
    const unsigned short* Kg = Kb + (((size_t)(b * NS + s)) * NSEQ) * DH;
    const unsigned short* Vg = Vt + (size_t)b * 128 * NSEQ;

    // Q fragments in registers (B-operand): q = wid*16 + lrow, k = kk*32 + lgrp*8
    bf16x8 qf[2];
    {
        const unsigned short* qrow = Qg + (wid * 16 + lrow) * DH + lgrp * 8;
        qf[0] = *(const bf16x8_ma*)(qrow);
        qf[1] = *(const bf16x8_ma*)(qrow + 32);
    }

    const int r0 = tid >> 3, cc = tid & 7;
    const unsigned short* kp = Kg + (size_t)r0 * DH + cc * 8;
    const unsigned short* vp = Vg + (size_t)r0 * NSEQ + cc * 8;
    const int offk = (r0 * 128 + cc * 16) ^ ((r0 & 7) << 4);
    char* sPw = smem + 49152 + wid * 2048;

    uint4 kreg[2], vreg[4];
#define LOADT(KT) do {                                                        \
        const unsigned short* kq_ = kp + (size_t)(KT) * 64 * DH;              \
        kreg[0] = *(const uint4_ma*)(kq_);                                    \
        kreg[1] = *(const uint4_ma*)(kq_ + 32 * DH);                          \
        const unsigned short* vq_ = vp + (KT) * 64;                           \
        vreg[0] = *(const uint4_ma*)(vq_);                                    \
        vreg[1] = *(const uint4_ma*)(vq_ + (size_t)32 * NSEQ);                \
        vreg[2] = *(const uint4_ma*)(vq_ + (size_t)64 * NSEQ);                \
        vreg[3] = *(const uint4_ma*)(vq_ + (size_t)96 * NSEQ);                \
    } while (0)
#define STORET(BUF) do {                                                      \
        char* kb_ = smem + (BUF) * 8192;                                      \
        *(uint4_ma*)(kb_ + offk)        = kreg[0];                            \
        *(uint4_ma*)(kb_ + offk + 4096) = kreg[1];                            \
        char* vb_ = smem + 16384 + (BUF) * 16384;                             \
        *(uint4_ma*)(vb_ + offk)         = vreg[0];                           \
        *(uint4_ma*)(vb_ + offk + 4096)  = vreg[1];                           \
        *(uint4_ma*)(vb_ + offk + 8192)  = vreg[2];                           \
        *(uint4_ma*)(vb_ + offk + 12288) = vreg[3];                           \
    } while (0)

    f32x4 oacc[8];
#pragma unroll
    for (int df = 0; df < 8; ++df) oacc[df] = (f32x4){0.f, 0.f, 0.f, 0.f};
    float m_ = -1e30f, l_ = 0.f;

    const int NT = NSEQ / 64;
    LOADT(0);
    STORET(0);
    LOADT(1);

    for (int kt = 0; kt < NT; ++kt) {
        const int cur = kt & 1;
        __syncthreads();   // prev iter's reads of buf[cur^1] done; buf[cur] writes visible
        if (kt + 1 < NT) STORET(cur ^ 1);
        if (kt + 2 < NT) LOADT(kt + 2);

        const char* kb = smem + cur * 8192;
        const char* vb = smem + 16384 + cur * 16384;

        // ---- S^T = K x Q^T : lane holds S[q=lrow][kv = nf*16 + lgrp*4 + r] ----
        f32x4 st[4];
#pragma unroll
        for (int nf = 0; nf < 4; ++nf) st[nf] = (f32x4){0.f, 0.f, 0.f, 0.f};
        __builtin_amdgcn_s_setprio(1);
#pragma unroll
        for (int kk = 0; kk < 2; ++kk) {
#pragma unroll
            for (int nf = 0; nf < 4; ++nf) {
                int row = nf * 16 + lrow;
                bf16x8 kf = *(bf16x8_ma*)(kb + ((row * 128 + kk * 64 + lgrp * 16) ^ ((row & 7) << 4)));
                st[nf] = __builtin_amdgcn_mfma_f32_16x16x32_bf16(kf, qf[kk], st[nf], 0, 0, 0);
            }
        }
        __builtin_amdgcn_s_setprio(0);

        // ---- online softmax, log2 domain, T13 defer-rescale ----
        float mx = st[0][0];
#pragma unroll
        for (int nf = 0; nf < 4; ++nf)
#pragma unroll
            for (int r = 0; r < 4; ++r) mx = fmaxf(mx, st[nf][r]);
        mx = fmaxf(mx, __shfl_xor(mx, 16));
        mx = fmaxf(mx, __shfl_xor(mx, 32));
        if (__any(mx > m_ + 8.f)) {
            float mnew = fmaxf(m_, mx);
            float alpha = __builtin_exp2f(m_ - mnew);
#pragma unroll
            for (int df = 0; df < 8; ++df) oacc[df] = oacc[df] * alpha;
            l_ *= alpha;
            m_ = mnew;
        }
        float rs = 0.f;
#pragma unroll
        for (int nf = 0; nf < 4; ++nf)
#pragma unroll
            for (int r = 0; r < 4; ++r) {
                float p = __builtin_exp2f(st[nf][r] - m_);
                st[nf][r] = p;
                rs += p;
            }
        rs += __shfl_xor(rs, 16);
        rs += __shfl_xor(rs, 32);
        l_ += rs;

        // ---- P -> LDS (packed b64, wave-local) ----
        const int pswz = (lrow & 7) << 4;
#pragma unroll
        for (int nf = 0; nf < 4; ++nf) {
            uint2 w;
            w.x = cvt_pk_bf16(st[nf][0], st[nf][1]);
            w.y = cvt_pk_bf16(st[nf][2], st[nf][3]);
            *(uint2_ma*)(sPw + ((lrow * 128 + nf * 32 + lgrp * 8) ^ pswz)) = w;
        }

        // ---- O^T += V^T x P^T : lane holds O[q=lrow][d = df*16 + lgrp*4 + r] ----
        __builtin_amdgcn_s_setprio(1);
#pragma unroll
        for (int kkv = 0; kkv < 2; ++kkv) {
            bf16x8 pf = *(bf16x8_ma*)(sPw + ((lrow * 128 + kkv * 64 + lgrp * 16) ^ pswz));
#pragma unroll
            for (int df = 0; df < 8; ++df) {
                int row = df * 16 + lrow;
                bf16x8 vf = *(bf16x8_ma*)(vb + ((row * 128 + kkv * 64 + lgrp * 16) ^ ((row & 7) << 4)));
                oacc[df] = __builtin_amdgcn_mfma_f32_16x16x32_bf16(vf, pf, oacc[df], 0, 0, 0);
            }
        }
        __builtin_amdgcn_s_setprio(0);
    }
#undef LOADT
#undef STORET

    // ---- retrieval epilogue (register-only; u = x@Wc already has 0.125*log2e) ----
    {
        const int n = qt * 64 + wid * 16 + lrow;
        const float* ug = RU + ((((size_t)(b * NS + s)) * NSEQ) + n) * DH + lgrp * 4;
        float s0 = 0.f, s1 = 0.f;
#pragma unroll
        for (int df = 0; df < 4; ++df) {
            float4 u4 = *(const float4_ma*)(ug + df * 16);
            s0 += oacc[df][0] * u4.x + oacc[df][1] * u4.y + oacc[df][2] * u4.z + oacc[df][3] * u4.w;
            s1 += oacc[df + 4][0] * u4.x + oacc[df + 4][1] * u4.y + oacc[df + 4][2] * u4.z + oacc[df + 4][3] * u4.w;
        }
        s0 += __shfl_xor(s0, 16); s0 += __shfl_xor(s0, 32);
        s1 += __shfl_xor(s1, 16); s1 += __shfl_xor(s1, 32);
        float invl = 1.f / l_;
        float r0 = s0 * invl, r1 = s1 * invl;
        float mm = fmaxf(r0, r1);
        float e0 = __builtin_exp2f(r0 - mm), e1 = __builtin_exp2f(r1 - mm);
        float w = invl / (e0 + e1);
        float a0 = e0 * w, a1 = e1 * w;

        unsigned short* dst = O1b + ((size_t)(b * NSEQ + n)) * (NS * DH) + s * DH + lgrp * 4;
#pragma unroll
        for (int df = 0; df < 4; ++df) {
            float c0 = a0 * oacc[df][0] + a1 * oacc[df + 4][0];
            float c1 = a0 * oacc[df][1] + a1 * oacc[df + 4][1];
            float c2 = a0 * oacc[df][2] + a1 * oacc[df + 4][2];
            float c3 = a0 * oacc[df][3] + a1 * oacc[df + 4][3];
            uint2 o2;
            o2.x = cvt_pk_bf16(c0, c1);
            o2.y = cvt_pk_bf16(c2, c3);
            *(uint2_ma*)(dst + df * 16) = o2;
        }
    }
}

// ============ Kernel 3: output GEMM (bf16 MFMA) ============
__global__ __launch_bounds__(256) void out_mfma_k(
    const unsigned short* __restrict__ A, const unsigned short* __restrict__ Bw,
    float* __restrict__ C)
{
    __shared__ __align__(16) char smem[24576];
    const int tid = threadIdx.x;
    const int bn = blockIdx.x, bm = blockIdx.y;
    const int wid = tid >> 6, lane = tid & 63;
    const int wm = wid >> 1, wn = wid & 1;
    const int lrow = lane & 15, lgrp = lane >> 4;
    const int KD = NS * DH;   // 512

    f32x4 acc[4][2];
#pragma unroll
    for (int i = 0; i < 4; ++i)
#pragma unroll
        for (int j = 0; j < 2; ++j) acc[i][j] = (f32x4){0.f, 0.f, 0.f, 0.f};

    for (int kt = 0; kt < KD / 64; ++kt) {
        __syncthreads();
#pragma unroll
        for (int p = 0; p < 4; ++p) {
            int c = tid + p * 256;
            int r = c >> 3, cc = c & 7;
            *(uint4_ma*)(smem + ((r * 128 + cc * 16) ^ ((r & 7) << 4))) =
                *(const uint4_ma*)(A + (size_t)(bm * 128 + r) * KD + kt * 64 + cc * 8);
        }
#pragma unroll
        for (int p = 0; p < 2; ++p) {
            int c = tid + p * 256;
            int r = c >> 3, cc = c & 7;
            *(uint4_ma*)(smem + 16384 + ((r * 128 + cc * 16) ^ ((r & 7) << 4))) =
                *(const uint4_ma*)(Bw + (size_t)(bn * 64 + r) * KD + kt * 64 + cc * 8);
        }
        __syncthreads();
#pragma unroll
        for (int ks = 0; ks < 2; ++ks) {
            bf16x8 bfr[2];
#pragma unroll
            for (int nf = 0; nf < 2; ++nf) {
                int rb = wn * 32 + nf * 16 + lrow;
                bfr[nf] = *(bf16x8_ma*)(smem + 16384 + ((rb * 128 + ks * 64 + lgrp * 16) ^ ((rb & 7) << 4)));
            }
#pragma unroll
            for (int mf = 0; mf < 4; ++mf) {
                int ra = wm * 64 + mf * 16 + lrow;
                bf16x8 af = *(bf16x8_ma*)(smem + ((ra * 128 + ks * 64 + lgrp * 16) ^ ((ra & 7) << 4)));
#pragma unroll
                for (int nf = 0; nf < 2; ++nf)
                    acc[mf][nf] = __builtin_amdgcn_mfma_f32_16x16x32_bf16(af, bfr[nf], acc[mf][nf], 0, 0, 0);
            }
        }
    }

#pragma unroll
    for (int mf = 0; mf < 4; ++mf) {
#pragma unroll
        for (int nf = 0; nf < 2; ++nf) {
            int j0 = bn * 64 + wn * 32 + nf * 16 + lrow;
            int m0 = bm * 128 + wm * 64 + mf * 16 + lgrp * 4;
#pragma unroll
            for (int r = 0; r < 4; ++r)
                C[(size_t)(m0 + r) * KDIM + j0] = acc[mf][nf][r];
        }
    }
}

extern "C" void kernel_launch(void* const* d_in, const int* in_sizes, int n_in,
                              void* d_out, int out_size, void* d_ws, size_t ws_size,
                              hipStream_t stream)
{
    const float* x    = (const float*)d_in[0];
    const float* Wsq  = (const float*)d_in[1];
    const float* Wsk  = (const float*)d_in[2];
    const float* Wrv  = (const float*)d_in[3];
    const float* Wrq  = (const float*)d_in[4];
    const float* Wrk  = (const float*)d_in[5];
    const float* Wout = (const float*)d_in[6];
    float* out = (float*)d_out;

    // workspace layout (37.3 MB)
    float* RU            = (float*)d_ws;                        // [2][8][2048][64] f32, 8 MB
    unsigned short* Wt   = (unsigned short*)(RU + (size_t)2 * NS * NSEQ * DH);  // [1664][1024], 3.25 MB
    unsigned short* Wot  = Wt + (size_t)1664 * KDIM;            // [1024][512], 1 MB
    unsigned short* Qb   = Wot + (size_t)KDIM * 512;            // [2][8][2048][64], 4 MB
    unsigned short* Kb   = Qb + (size_t)2 * NS * NSEQ * DH;     // 4 MB
    unsigned short* Vtb  = Kb + (size_t)2 * NS * NSEQ * DH;     // [2][128][2048], 1 MB
    unsigned short* xh   = Vtb + (size_t)2 * 128 * NSEQ;        // [4096][1024], 8 MB
    unsigned short* xl   = xh + (size_t)4096 * KDIM;            // 8 MB
    unsigned short* O1b  = xh;  // alias: xh dead after proj_mfma_k

    prep_w_k<<<544, 256, 0, stream>>>(Wsq, Wsk, Wrq, Wrv, Wout, Wt, Wot);
    prep_wc_k<<<dim3(8, 16), 256, 0, stream>>>(Wrq, Wrk, Wt);
    prep_x_k<<<2048, 256, 0, stream>>>(x, xh, xl);
    proj_mfma_k<<<dim3(26, 32), 256, 0, stream>>>(xh, xl, Wt, Qb, Kb, RU, Vtb);
    attn_mfma_k<<<dim3(NSEQ / 64, NS, 2), 256, 0, stream>>>(Qb, Kb, Vtb, RU, O1b);
    out_mfma_k<<<dim3(16, 32), 256, 0, stream>>>(O1b, Wot, out);
}